// Round 4
// baseline (100.110 us; speedup 1.0000x reference)
//
#include <hip/hip_runtime.h>
#include <stdint.h>

#define Bd 4
#define Nn 48
#define Mm 48
#define Hh 192
#define Ww 640
#define HW (Hh*Ww)            // 122880 pixels per mask
#define WORDS (HW/64)         // 1920 uint64 words per mask
#define PIX_PER_WAVE 4096     // 4 iters x 64 lanes x 16 px; HW % 4096 == 0 -> wave never straddles masks
#define WAVES_A ((Bd*Nn*HW)/PIX_PER_WAVE)   // 5760

// ---------------------------------------------------------------------------
// K1: pack fp32 binary masks into bit masks + fused per-mask popcount.
// No LDS, no barrier, no tail: lane owns 64 consecutive pixels split into
// 4 iterations of 16 px (4x float4, consecutive addresses). All 16 loads are
// independent -> deep MLP. Each iteration's 16-bit mask is stored directly as
// a ushort (little-endian ushort order == uint64 bit order, so pack layout is
// identical to uint64 words). Popcount accumulates in-register; one
// wave-reduce + one atomicAdd per wave (30 per counter).
// ---------------------------------------------------------------------------
__global__ void pack_kernel(const float* __restrict__ a, const float* __restrict__ b,
                            ushort* __restrict__ packA, ushort* __restrict__ packB,
                            unsigned int* __restrict__ saInt, unsigned int* __restrict__ sbInt) {
    int wave = blockIdx.x * (blockDim.x >> 6) + (threadIdx.x >> 6);
    const int lane = threadIdx.x & 63;
    const float* src; ushort* dst; unsigned int* cnt;
    if (wave < WAVES_A) { src = a; dst = packA; cnt = saInt; }
    else                { src = b; dst = packB; cnt = sbInt; wave -= WAVES_A; }
    const long long waveBase = (long long)wave * PIX_PER_WAVE;
    // lane's 64 consecutive pixels start here (within the wave's 4096-px span)
    const float4* f4 = reinterpret_cast<const float4*>(src + waveBase + (long long)lane * 64);
    unsigned int s = 0;
    #pragma unroll
    for (int i = 0; i < 4; ++i) {
        float4 v0 = f4[i * 4 + 0];
        float4 v1 = f4[i * 4 + 1];
        float4 v2 = f4[i * 4 + 2];
        float4 v3 = f4[i * 4 + 3];
        unsigned int bits =
              (v0.x > 0.0f ? 1u      : 0u) | (v0.y > 0.0f ? 1u << 1  : 0u)
            | (v0.z > 0.0f ? 1u << 2 : 0u) | (v0.w > 0.0f ? 1u << 3  : 0u)
            | (v1.x > 0.0f ? 1u << 4 : 0u) | (v1.y > 0.0f ? 1u << 5  : 0u)
            | (v1.z > 0.0f ? 1u << 6 : 0u) | (v1.w > 0.0f ? 1u << 7  : 0u)
            | (v2.x > 0.0f ? 1u << 8 : 0u) | (v2.y > 0.0f ? 1u << 9  : 0u)
            | (v2.z > 0.0f ? 1u <<10 : 0u) | (v2.w > 0.0f ? 1u << 11 : 0u)
            | (v3.x > 0.0f ? 1u <<12 : 0u) | (v3.y > 0.0f ? 1u << 13 : 0u)
            | (v3.z > 0.0f ? 1u <<14 : 0u) | (v3.w > 0.0f ? 1u << 15 : 0u);
        // ushort index = pixel_base / 16
        dst[(waveBase >> 4) + lane * 4 + i] = (ushort)bits;
        s += __popc(bits);
    }
    #pragma unroll
    for (int off = 32; off; off >>= 1) s += __shfl_down(s, off);
    if (lane == 0)
        atomicAdd(&cnt[(int)(waveBase / HW)], s);
}

// ---------------------------------------------------------------------------
// K2: one wave per (b,n,m) pair. inter = sum popcount(A&B); q-test exactly as
// the float32 reference; set bit m of qmask[b][n] when qualifying.
// ---------------------------------------------------------------------------
__global__ void pair_kernel(const uint64_t* __restrict__ packA, const uint64_t* __restrict__ packB,
                            const unsigned int* __restrict__ saInt, const unsigned int* __restrict__ sbInt,
                            unsigned long long* __restrict__ qmask) {
    int wave = blockIdx.x * (blockDim.x >> 6) + (threadIdx.x >> 6);
    int lane = threadIdx.x & 63;
    int bb = wave / (Nn * Mm);
    int nm = wave % (Nn * Mm);
    int n = nm / Mm, m = nm % Mm;
    const uint64_t* A  = packA + (size_t)(bb * Nn + n) * WORDS;
    const uint64_t* Bp = packB + (size_t)(bb * Mm + m) * WORDS;
    unsigned int s = 0;
    #pragma unroll 5
    for (int w = lane; w < WORDS; w += 64)
        s += (unsigned int)__popcll(A[w] & Bp[w]);
    #pragma unroll
    for (int off = 32; off; off >>= 1) s += __shfl_down(s, off);
    if (lane == 0) {
        float inter = (float)s;
        float un = (float)saInt[bb * Nn + n] + (float)sbInt[bb * Mm + m] - inter;
        if (inter / fmaxf(un, 1.0f) > 0.8f)
            atomicOr(&qmask[bb * Nn + n], 1ull << m);
    }
}

// ---------------------------------------------------------------------------
// K3+K4 fused: per word, OR of (a_n ^ b_m) over qualifying pairs -> LDS ->
// coalesced float4 expansion to the output.
// ---------------------------------------------------------------------------
__global__ void words_expand_kernel(const uint64_t* __restrict__ packA,
                                    const uint64_t* __restrict__ packB,
                                    const unsigned long long* __restrict__ qmask,
                                    float* __restrict__ out) {
    __shared__ uint64_t sw[256];
    const int t = threadIdx.x;
    const int i = blockIdx.x * 256 + t;       // word index in [0, Bd*WORDS)
    const int bb = i / WORDS, w = i % WORDS;
    uint64_t acc = 0;
    for (int n = 0; n < Nn; ++n) {
        unsigned long long qm = qmask[bb * Nn + n];
        if (!qm) continue;
        uint64_t aw = packA[(size_t)(bb * Nn + n) * WORDS + w];
        while (qm) {
            int m = __ffsll((long long)qm) - 1;
            qm &= qm - 1;
            acc |= aw ^ packB[(size_t)(bb * Mm + m) * WORDS + w];
        }
        if (acc == ~0ull) break;              // word fully covered
    }
    sw[t] = acc;
    __syncthreads();
    float4* out4 = reinterpret_cast<float4*>(out) + (size_t)blockIdx.x * 4096;
    #pragma unroll
    for (int k = 0; k < 16; ++k) {
        int p0 = k * 1024 + 4 * t;            // first of this thread's 4 pixels
        uint64_t wv = sw[p0 >> 6];            // broadcast within 16-lane groups
        unsigned int bits = (unsigned int)(wv >> (p0 & 63)) & 0xFu;
        float4 f;
        f.x = (bits & 1u) ? 0.0f : 1.0f;
        f.y = (bits & 2u) ? 0.0f : 1.0f;
        f.z = (bits & 4u) ? 0.0f : 1.0f;
        f.w = (bits & 8u) ? 0.0f : 1.0f;
        out4[k * 256 + t] = f;                // 4KB contiguous per instruction
    }
}

extern "C" void kernel_launch(void* const* d_in, const int* in_sizes, int n_in,
                              void* d_out, int out_size, void* d_ws, size_t ws_size,
                              hipStream_t stream) {
    const float* a = (const float*)d_in[0];   // stereo_warped_target  [B,N,H,W]
    const float* b = (const float*)d_in[1];   // temporal_warped_target [B,M,H,W]
    float* out = (float*)d_out;               // [B,1,H,W]

    uint8_t* ws = (uint8_t*)d_ws;
    const size_t szPack = (size_t)Bd * Nn * WORDS * sizeof(uint64_t);  // 2.95 MB (N==M)
    uint64_t* packA = (uint64_t*)(ws);
    uint64_t* packB = (uint64_t*)(ws + szPack);
    unsigned int* saInt = (unsigned int*)(ws + 2 * szPack);
    unsigned int* sbInt = saInt + Bd * Nn;
    unsigned long long* qmask = (unsigned long long*)(ws + 2 * szPack + (size_t)Bd * (Nn + Mm) * 4);

    // zero the atomically-accumulated arrays (counters + qmask) in one memset
    hipMemsetAsync(saInt, 0, (size_t)Bd * (Nn + Mm) * 4 + (size_t)Bd * Nn * 8, stream);

    // K1: pack + popcount sums
    {
        int waves = 2 * WAVES_A;                  // 11520 waves
        int blocks = waves / 4;                   // 2880 blocks x 256 threads
        pack_kernel<<<blocks, 256, 0, stream>>>(a, b, (ushort*)packA, (ushort*)packB, saInt, sbInt);
    }
    // K2: pairwise IoU -> qmask
    {
        int pairs = Bd * Nn * Mm;          // 9216 waves
        int blocks = pairs / 4;            // 4 waves per 256-thread block
        pair_kernel<<<blocks, 256, 0, stream>>>(packA, packB, saInt, sbInt, qmask);
    }
    // K3+K4 fused: zero-words + float expansion
    {
        int blocks = (Bd * WORDS) / 256;   // 30
        words_expand_kernel<<<blocks, 256, 0, stream>>>(packA, packB, qmask, out);
    }
}